// Round 1
// 1211.100 us; speedup vs baseline: 1.0375x; 1.0375x over previous
//
#include <hip/hip_runtime.h>
#include <cstdint>

#define N_NODES 524288
#define E_EDGES 8388608
#define F_IN 128
#define HID 8
#define B_GRAPHS 64
#define NPG 8192
#define NPG_SHIFT 13

// flag bits
#define FT  1u   // target
#define FS1 2u   // needs x2
#define FS2 4u   // needs x1
#define FS3 8u   // needs hp

// edge-list capacities (expected ~1k / ~17k / ~296k)
#define L1CAP 8192
#define L2CAP 65536
#define L3CAP 1048576

#define EBLK 512
#define NEBLK (E_EDGES / EBLK)   // 16384

// ---------------- zero the stateful span of the workspace ----------------
__global__ void clear_kernel(float4* __restrict__ p, int n4) {
    int i = blockIdx.x * blockDim.x + threadIdx.x;
    int st = gridDim.x * blockDim.x;
    float4 z = make_float4(0.f, 0.f, 0.f, 0.f);
    for (; i < n4; i += st) p[i] = z;
}

// ---------------- mark target nodes ----------------
__global__ void mark_kernel(const int* __restrict__ tgt, unsigned int* __restrict__ flags) {
    int g = threadIdx.x;
    if (g < B_GRAPHS) flags[g * NPG + tgt[g]] = FT | FS1 | FS2 | FS3;
}

// ---------------- pass 1: degree histogram + mark S1 + collect L1 ----------
__global__ __launch_bounds__(EBLK) void pass1_kernel(
        const int* __restrict__ src, const int* __restrict__ dst,
        unsigned int* __restrict__ flags, unsigned int* __restrict__ deg,
        int2* __restrict__ L1, int* __restrict__ cnt) {
    __shared__ int lcnt;
    __shared__ int lbase;
    if (threadIdx.x == 0) lcnt = 0;
    __syncthreads();
    int e = blockIdx.x * EBLK + threadIdx.x;
    int d = dst[e];
    atomicAdd(&deg[d], 1u);
    bool m = (flags[d] & FT) != 0;   // bit0 only written before this kernel
    int s = 0, pos = 0;
    if (m) {
        s = src[e];
        atomicOr(&flags[s], FS1 | FS2 | FS3);
        pos = atomicAdd(&lcnt, 1);
    }
    __syncthreads();
    if (threadIdx.x == 0 && lcnt) lbase = atomicAdd(cnt, lcnt);
    __syncthreads();
    if (m) {
        int idx = lbase + pos;
        if (idx < L1CAP) L1[idx] = make_int2(s, d);
    }
}

// ---------------- passes 2/3: frontier expansion + edge collection ---------
template <unsigned int CHECK, unsigned int SETM, int CAP>
__global__ __launch_bounds__(EBLK) void pass_mark_kernel(
        const int* __restrict__ src, const int* __restrict__ dst,
        unsigned int* __restrict__ flags,
        int2* __restrict__ L, int* __restrict__ cnt) {
    __shared__ int lcnt;
    __shared__ int lbase;
    if (threadIdx.x == 0) lcnt = 0;
    __syncthreads();
    int e = blockIdx.x * EBLK + threadIdx.x;
    int d = dst[e];
    // CHECK bit was fully written by the previous kernel; this kernel only ORs
    // strictly lower-priority bits (SETM), so the test is race-free.
    bool m = (flags[d] & CHECK) != 0;
    int s = 0, pos = 0;
    if (m) {
        s = src[e];
        atomicOr(&flags[s], SETM);
        pos = atomicAdd(&lcnt, 1);
    }
    __syncthreads();
    if (threadIdx.x == 0 && lcnt) lbase = atomicAdd(cnt, lcnt);
    __syncthreads();
    if (m) {
        int idx = lbase + pos;
        if (idx < CAP) L[idx] = make_int2(s, d);
    }
}

// ---------------- dis = rsqrt(deg + 1) ----------------
__global__ void dis_kernel(const unsigned int* __restrict__ deg, float* __restrict__ dis) {
    int i = blockIdx.x * blockDim.x + threadIdx.x;
    dis[i] = rsqrtf((float)deg[i] + 1.0f);
}

// ---------------- hps = (x @ W1) * dis, only at S3 nodes ----------------
__global__ void mm1s_kernel(const float* __restrict__ x, const float* __restrict__ W1,
                            const unsigned int* __restrict__ flags,
                            const float* __restrict__ dis, float* __restrict__ hps) {
    __shared__ float w[F_IN * HID];
    for (int t = threadIdx.x; t < F_IN * HID; t += blockDim.x) w[t] = W1[t];
    __syncthreads();
    int row = blockIdx.x * blockDim.x + threadIdx.x;
    if (!(flags[row] & FS3)) return;
    const float4* xr = (const float4*)(x + (size_t)row * F_IN);
    float acc[HID] = {0.f,0.f,0.f,0.f,0.f,0.f,0.f,0.f};
    #pragma unroll 8
    for (int it = 0; it < F_IN / 4; ++it) {
        float4 xv = xr[it];
        const float* wr = &w[it * 4 * HID];
        #pragma unroll
        for (int j = 0; j < HID; ++j)
            acc[j] += xv.x * wr[j] + xv.y * wr[HID + j] + xv.z * wr[2 * HID + j] + xv.w * wr[3 * HID + j];
    }
    float di = dis[row];
    float4* o = (float4*)(hps + (size_t)row * HID);
    o[0] = make_float4(acc[0] * di, acc[1] * di, acc[2] * di, acc[3] * di);
    o[1] = make_float4(acc[4] * di, acc[5] * di, acc[6] * di, acc[7] * di);
}

// ---------------- edge-centric scatter: acc[d] += hsrc[s] (8 floats) -------
__global__ void edge_gather_kernel(const int2* __restrict__ L, const int* __restrict__ cntp,
                                   int cap, const float* __restrict__ hsrc,
                                   float* __restrict__ acc) {
    int n = cntp[0];
    if (n > cap) n = cap;
    int st = gridDim.x * blockDim.x;
    for (int i = blockIdx.x * blockDim.x + threadIdx.x; i < n; i += st) {
        int2 e = L[i];
        const float4* h = (const float4*)(hsrc + (size_t)e.x * HID);
        float4 a = h[0], b = h[1];
        float* o = acc + (size_t)e.y * HID;
        atomicAdd(o + 0, a.x); atomicAdd(o + 1, a.y);
        atomicAdd(o + 2, a.z); atomicAdd(o + 3, a.w);
        atomicAdd(o + 4, b.x); atomicAdd(o + 5, b.y);
        atomicAdd(o + 6, b.z); atomicAdd(o + 7, b.w);
    }
}

// ---- fin1: x1 = relu(di*(acc + hps) + b1); hps <- (x1 @ W2) * di  (S2) ----
__global__ void fin1_kernel(const unsigned int* __restrict__ flags, const float* __restrict__ dis,
                            float* __restrict__ hps, const float* __restrict__ b1v,
                            const float* __restrict__ W2, float* __restrict__ x1) {
    __shared__ float w[HID * HID];
    if (threadIdx.x < HID * HID) w[threadIdx.x] = W2[threadIdx.x];
    __syncthreads();
    int i = blockIdx.x * blockDim.x + threadIdx.x;
    if (!(flags[i] & FS2)) return;
    float di = dis[i];
    float4* xp = (float4*)(x1 + (size_t)i * HID);
    float4* hp = (float4*)(hps + (size_t)i * HID);
    float4 a0 = xp[0], a1 = xp[1], h0 = hp[0], h1 = hp[1];
    float v[HID];
    v[0] = fmaxf(di * (a0.x + h0.x) + b1v[0], 0.f);
    v[1] = fmaxf(di * (a0.y + h0.y) + b1v[1], 0.f);
    v[2] = fmaxf(di * (a0.z + h0.z) + b1v[2], 0.f);
    v[3] = fmaxf(di * (a0.w + h0.w) + b1v[3], 0.f);
    v[4] = fmaxf(di * (a1.x + h1.x) + b1v[4], 0.f);
    v[5] = fmaxf(di * (a1.y + h1.y) + b1v[5], 0.f);
    v[6] = fmaxf(di * (a1.z + h1.z) + b1v[6], 0.f);
    v[7] = fmaxf(di * (a1.w + h1.w) + b1v[7], 0.f);
    xp[0] = make_float4(v[0], v[1], v[2], v[3]);
    xp[1] = make_float4(v[4], v[5], v[6], v[7]);
    float o[HID];
    #pragma unroll
    for (int j = 0; j < HID; ++j) {
        float sj = 0.f;
        #pragma unroll
        for (int k = 0; k < HID; ++k) sj += v[k] * w[k * HID + j];
        o[j] = sj * di;
    }
    hp[0] = make_float4(o[0], o[1], o[2], o[3]);
    hp[1] = make_float4(o[4], o[5], o[6], o[7]);
}

// ---- fin2: x2 = relu(di*(acc + hps) + b2)  (S1 nodes) ----
__global__ void fin2_kernel(const unsigned int* __restrict__ flags, const float* __restrict__ dis,
                            const float* __restrict__ hps, const float* __restrict__ b2v,
                            float* __restrict__ x2) {
    int i = blockIdx.x * blockDim.x + threadIdx.x;
    if (!(flags[i] & FS1)) return;
    float di = dis[i];
    float4* xp = (float4*)(x2 + (size_t)i * HID);
    const float4* hp = (const float4*)(hps + (size_t)i * HID);
    float4 a0 = xp[0], a1 = xp[1], h0 = hp[0], h1 = hp[1];
    xp[0] = make_float4(fmaxf(di * (a0.x + h0.x) + b2v[0], 0.f),
                        fmaxf(di * (a0.y + h0.y) + b2v[1], 0.f),
                        fmaxf(di * (a0.z + h0.z) + b2v[2], 0.f),
                        fmaxf(di * (a0.w + h0.w) + b2v[3], 0.f));
    xp[1] = make_float4(fmaxf(di * (a1.x + h1.x) + b2v[4], 0.f),
                        fmaxf(di * (a1.y + h1.y) + b2v[5], 0.f),
                        fmaxf(di * (a1.z + h1.z) + b2v[6], 0.f),
                        fmaxf(di * (a1.w + h1.w) + b2v[7], 0.f));
}

// ---- head gather: a3[g] += dot(x2[s], W3) * dis[s] over L1 edges ----
__global__ void headg_kernel(const int2* __restrict__ L1, const int* __restrict__ cntp,
                             const float* __restrict__ x2, const float* __restrict__ dis,
                             const float* __restrict__ W3, float* __restrict__ a3) {
    __shared__ float w3[HID];
    if (threadIdx.x < HID) w3[threadIdx.x] = W3[threadIdx.x];
    __syncthreads();
    int n = cntp[0];
    if (n > L1CAP) n = L1CAP;
    int st = gridDim.x * blockDim.x;
    for (int i = blockIdx.x * blockDim.x + threadIdx.x; i < n; i += st) {
        int2 e = L1[i];
        const float* xs = x2 + (size_t)e.x * HID;
        float h = 0.f;
        #pragma unroll
        for (int j = 0; j < HID; ++j) h += xs[j] * w3[j];
        atomicAdd(&a3[e.y >> NPG_SHIFT], h * dis[e.x]);
    }
}

// ---- head final: assemble feats, MLP ----
__global__ void headf_kernel(const int* __restrict__ tgt, const float* __restrict__ x1,
                             const float* __restrict__ x2, const float* __restrict__ dis,
                             const float* __restrict__ a3, const float* __restrict__ W3,
                             const float* __restrict__ b3, const float* __restrict__ Wl1,
                             const float* __restrict__ bl1, const float* __restrict__ Wl2,
                             const float* __restrict__ bl2, float* __restrict__ out) {
    int g = threadIdx.x;
    if (g >= B_GRAPHS) return;
    size_t t = (size_t)g * NPG + tgt[g];
    float di = dis[t];
    float f[17];
    #pragma unroll
    for (int j = 0; j < HID; ++j) f[j] = x1[t * HID + j];
    #pragma unroll
    for (int j = 0; j < HID; ++j) f[8 + j] = x2[t * HID + j];
    float h3 = 0.f;
    #pragma unroll
    for (int j = 0; j < HID; ++j) h3 += f[8 + j] * W3[j];
    f[16] = fmaxf(a3[g] * di + h3 * di * di + b3[0], 0.f);
    float o0 = bl2[0], o1 = bl2[1];
    #pragma unroll
    for (int j = 0; j < 16; ++j) {
        float z = bl1[j];
        #pragma unroll
        for (int k = 0; k < 17; ++k) z += f[k] * Wl1[k * 16 + j];
        z = fmaxf(z, 0.f);
        o0 += z * Wl2[j * 2 + 0];
        o1 += z * Wl2[j * 2 + 1];
    }
    out[g * 2 + 0] = o0;
    out[g * 2 + 1] = o1;
}

extern "C" void kernel_launch(void* const* d_in, const int* in_sizes, int n_in,
                              void* d_out, int out_size, void* d_ws, size_t ws_size,
                              hipStream_t stream) {
    const float* x  = (const float*)d_in[0];
    const int* ei   = (const int*)d_in[1];
    const int* src  = ei;
    const int* dst  = ei + E_EDGES;
    const int* tid  = (const int*)d_in[2];
    const float* W1 = (const float*)d_in[3];
    const float* b1 = (const float*)d_in[4];
    const float* W2 = (const float*)d_in[5];
    const float* b2 = (const float*)d_in[6];
    const float* W3 = (const float*)d_in[7];
    const float* b3 = (const float*)d_in[8];
    const float* Wl1 = (const float*)d_in[9];
    const float* bl1 = (const float*)d_in[10];
    const float* Wl2 = (const float*)d_in[11];
    const float* bl2 = (const float*)d_in[12];
    float* out = (float*)d_out;

    char* ws = (char*)d_ws;
    // ---- cleared span (contiguous): flags | deg | x1 | x2 | a3+cnt ----
    unsigned int* flags = (unsigned int*)(ws);                              // 2 MB
    unsigned int* deg   = (unsigned int*)(ws + 2097152);                    // 2 MB
    float* x1 = (float*)(ws + 4194304);                                     // 16 MB
    float* x2 = (float*)(ws + 4194304 + 16777216);                          // 16 MB
    float* a3 = (float*)(ws + 4194304 + 33554432);                          // 256 B
    int*  cnt = (int*)  (ws + 4194304 + 33554432 + 256);                    // cnt[0..2]
    const size_t CLEAR_BYTES = 4194304 + 33554432 + 512;                    // 37749248
    // ---- uncleared ----
    float* dis = (float*)(ws + 37749248);                                   // 2 MB
    float* hps = (float*)(ws + 39846400);                                   // 16 MB
    int2* L1 = (int2*)(ws + 56623616);                                      // 64 KB
    int2* L2 = (int2*)(ws + 56689152);                                      // 512 KB
    int2* L3 = (int2*)(ws + 57213440);                                      // 8 MB
    (void)ws_size;

    clear_kernel<<<2048, 256, 0, stream>>>((float4*)ws, (int)(CLEAR_BYTES / 16));
    mark_kernel<<<1, 64, 0, stream>>>(tid, flags);
    pass1_kernel<<<NEBLK, EBLK, 0, stream>>>(src, dst, flags, deg, L1, cnt + 0);
    dis_kernel<<<2048, 256, 0, stream>>>(deg, dis);
    pass_mark_kernel<FS1, FS2 | FS3, L2CAP><<<NEBLK, EBLK, 0, stream>>>(src, dst, flags, L2, cnt + 1);
    pass_mark_kernel<FS2, FS3, L3CAP><<<NEBLK, EBLK, 0, stream>>>(src, dst, flags, L3, cnt + 2);
    mm1s_kernel<<<2048, 256, 0, stream>>>(x, W1, flags, dis, hps);
    edge_gather_kernel<<<1024, 256, 0, stream>>>(L3, cnt + 2, L3CAP, hps, x1);
    fin1_kernel<<<2048, 256, 0, stream>>>(flags, dis, hps, b1, W2, x1);
    edge_gather_kernel<<<256, 256, 0, stream>>>(L2, cnt + 1, L2CAP, hps, x2);
    fin2_kernel<<<2048, 256, 0, stream>>>(flags, dis, hps, b2, x2);
    headg_kernel<<<8, 256, 0, stream>>>(L1, cnt + 0, x2, dis, W3, a3);
    headf_kernel<<<1, 64, 0, stream>>>(tid, x1, x2, dis, a3, W3, b3, Wl1, bl1, Wl2, bl2, out);
}

// Round 2
// 729.646 us; speedup vs baseline: 1.7221x; 1.6598x over previous
//
#include <hip/hip_runtime.h>
#include <cstdint>

#define N_NODES 524288
#define E_EDGES 8388608
#define F_IN 128
#define HID 8
#define B_GRAPHS 64
#define NPG 8192
#define NPG_SHIFT 13

// CSR build config (proven round-0 pipeline)
#define BUCKETS 1024
#define BSHIFT 9
#define BMASK 511
#define BUCKET_NODES 512
#define ABLK 512
#define ATHREADS 512
#define EPB (E_EDGES / ABLK)   // 16384 edges per phase-A block

#define SBUF_CAP 12288         // max edges per bucket slice (mean 8192, +45 sigma)

// ---------------- clear the 4 bitmap planes (256 KB) ----------------
__global__ void clear_kernel(int4* __restrict__ p) {
    p[blockIdx.x * blockDim.x + threadIdx.x] = make_int4(0, 0, 0, 0);
}

// ---------------- A1: per-block coarse histogram ----------------
__global__ void hist_kernel(const int* __restrict__ dst, int* __restrict__ M) {
    __shared__ int h[BUCKETS];
    int t = threadIdx.x;
    for (int j = t; j < BUCKETS; j += ATHREADS) h[j] = 0;
    __syncthreads();
    int base = blockIdx.x * EPB;
    #pragma unroll 4
    for (int k = 0; k < EPB / ATHREADS; ++k) {
        int d = dst[base + k * ATHREADS + t];
        atomicAdd(&h[d >> BSHIFT], 1);
    }
    __syncthreads();
    for (int j = t; j < BUCKETS; j += ATHREADS)
        M[(size_t)j * ABLK + blockIdx.x] = h[j];
}

// ---------------- A2: exclusive scan of each bucket row (over blocks) -------
__global__ void rowscan_kernel(int* __restrict__ M, int* __restrict__ btot) {
    __shared__ int tsum[256];
    int t = threadIdx.x;
    int* row = M + (size_t)blockIdx.x * ABLK;
    int v0 = row[t * 2], v1 = row[t * 2 + 1];
    int s = v0 + v1;
    tsum[t] = s;
    __syncthreads();
    for (int o = 1; o < 256; o <<= 1) {
        int y = (t >= o) ? tsum[t - o] : 0;
        __syncthreads();
        tsum[t] += y;
        __syncthreads();
    }
    int off = (t == 0) ? 0 : tsum[t - 1];
    row[t * 2] = off;
    row[t * 2 + 1] = off + v0;
    if (t == 255) btot[blockIdx.x] = off + s;
}

// ---------------- A3: exclusive scan of bucket totals -> bucket base --------
__global__ void basescan_kernel(const int* __restrict__ btot, int* __restrict__ base) {
    __shared__ int tsum[256];
    int t = threadIdx.x;
    int v[4], loc[4];
    int s = 0;
    #pragma unroll
    for (int k = 0; k < 4; ++k) {
        v[k] = btot[t * 4 + k];
        loc[k] = s;
        s += v[k];
    }
    tsum[t] = s;
    __syncthreads();
    for (int o = 1; o < 256; o <<= 1) {
        int y = (t >= o) ? tsum[t - o] : 0;
        __syncthreads();
        tsum[t] += y;
        __syncthreads();
    }
    int off = (t == 0) ? 0 : tsum[t - 1];
    #pragma unroll
    for (int k = 0; k < 4; ++k) base[t * 4 + k] = off + loc[k];
    if (t == 255) base[BUCKETS] = off + s;   // == E_EDGES
}

// ---------------- A4: bucket scatter via LDS cursors (no global atomics) ----
__global__ void scatter_kernel(const int* __restrict__ src, const int* __restrict__ dst,
                               const int* __restrict__ M, const int* __restrict__ base,
                               unsigned int* __restrict__ ebuf) {
    __shared__ int cur[BUCKETS];
    int t = threadIdx.x;
    for (int j = t; j < BUCKETS; j += ATHREADS)
        cur[j] = base[j] + M[(size_t)j * ABLK + blockIdx.x];
    __syncthreads();
    int eb = blockIdx.x * EPB;
    for (int k = 0; k < EPB / ATHREADS; ++k) {
        int e = eb + k * ATHREADS + t;
        int d = dst[e];
        int s = src[e];
        int p = atomicAdd(&cur[d >> BSHIFT], 1);
        ebuf[p] = ((unsigned int)(d & BMASK) << 19) | (unsigned int)s;
    }
}

// ---- B: per-bucket fine counting sort IN LDS, csr written in-place over ebuf
__global__ __launch_bounds__(256) void build_kernel(unsigned int* __restrict__ ebuf,
                                                    const int* __restrict__ base,
                                                    int* __restrict__ rowptr,
                                                    float* __restrict__ dis) {
    __shared__ unsigned int sbuf[SBUF_CAP];   // 48 KB
    __shared__ int cnt[BUCKET_NODES];
    __shared__ int cur[BUCKET_NODES];
    __shared__ int tsum[256];
    int t = threadIdx.x;
    int b = blockIdx.x;
    int e0 = base[b], e1 = base[b + 1];
    int n = e1 - e0;
    if (n > SBUF_CAP) n = SBUF_CAP;           // statistically impossible; safety
    cnt[t] = 0; cnt[t + 256] = 0;
    __syncthreads();
    for (int k = t; k < n; k += 256) {
        unsigned int w = ebuf[e0 + k];
        sbuf[k] = w;
        atomicAdd(&cnt[w >> 19], 1);
    }
    __syncthreads();
    int v0 = cnt[t * 2], v1 = cnt[t * 2 + 1];
    int s = v0 + v1;
    tsum[t] = s;
    __syncthreads();
    for (int o = 1; o < 256; o <<= 1) {
        int y = (t >= o) ? tsum[t - o] : 0;
        __syncthreads();
        tsum[t] += y;
        __syncthreads();
    }
    int off = (t == 0) ? 0 : tsum[t - 1];
    cur[t * 2] = off;
    cur[t * 2 + 1] = off + v0;
    int nodeBase = b * BUCKET_NODES;
    rowptr[nodeBase + t * 2]     = e0 + off;
    rowptr[nodeBase + t * 2 + 1] = e0 + off + v0;
    dis[nodeBase + t * 2]     = rsqrtf((float)v0 + 1.0f);
    dis[nodeBase + t * 2 + 1] = rsqrtf((float)v1 + 1.0f);
    if (b == 0 && t == 0) rowptr[N_NODES] = E_EDGES;
    __syncthreads();                           // all loads into LDS done
    for (int k = t; k < n; k += 256) {
        unsigned int w = sbuf[k];
        int p = atomicAdd(&cur[w >> 19], 1);
        ebuf[e0 + p] = w & 0x7FFFFu;           // csr: src ids, sorted by dst
    }
}

// ---------------- BFS1: targets -> planes, mark in-nbrs (S1) ----------------
__global__ void bfs1_kernel(const int* __restrict__ tgt, const int* __restrict__ rowptr,
                            const int* __restrict__ csr,
                            unsigned int* __restrict__ bm1, unsigned int* __restrict__ bm2,
                            unsigned int* __restrict__ bm3, unsigned int* __restrict__ bmT) {
    int g = threadIdx.x;
    if (g >= B_GRAPHS) return;
    int t = g * NPG + tgt[g];
    atomicOr(&bmT[t >> 5], 1u << (t & 31));
    atomicOr(&bm1[t >> 5], 1u << (t & 31));
    atomicOr(&bm2[t >> 5], 1u << (t & 31));
    atomicOr(&bm3[t >> 5], 1u << (t & 31));
    int e0 = rowptr[t], e1 = rowptr[t + 1];
    for (int k = e0; k < e1; ++k) {
        int s = csr[k];
        atomicOr(&bm1[s >> 5], 1u << (s & 31));
        atomicOr(&bm2[s >> 5], 1u << (s & 31));
        atomicOr(&bm3[s >> 5], 1u << (s & 31));
    }
}

// ---------------- BFS2: plane1 nodes -> mark in-nbrs into planes 2,3 --------
__global__ void bfs2_kernel(const int* __restrict__ rowptr, const int* __restrict__ csr,
                            const unsigned int* __restrict__ bm1,
                            unsigned int* __restrict__ bm2, unsigned int* __restrict__ bm3) {
    int i = blockIdx.x * blockDim.x + threadIdx.x;
    if (!((bm1[i >> 5] >> (i & 31)) & 1u)) return;
    int e0 = rowptr[i], e1 = rowptr[i + 1];
    for (int k = e0; k < e1; ++k) {
        int s = csr[k];
        atomicOr(&bm2[s >> 5], 1u << (s & 31));
        atomicOr(&bm3[s >> 5], 1u << (s & 31));
    }
}

// ---------------- BFS3: plane2 nodes -> mark in-nbrs into plane 3 -----------
__global__ void bfs3_kernel(const int* __restrict__ rowptr, const int* __restrict__ csr,
                            const unsigned int* __restrict__ bm2,
                            unsigned int* __restrict__ bm3) {
    int i = blockIdx.x * blockDim.x + threadIdx.x;
    if (!((bm2[i >> 5] >> (i & 31)) & 1u)) return;
    int e0 = rowptr[i], e1 = rowptr[i + 1];
    for (int k = e0; k < e1; ++k) {
        int s = csr[k];
        atomicOr(&bm3[s >> 5], 1u << (s & 31));
    }
}

// ---------------- hps = (x @ W1) * dis, only at plane3 nodes ----------------
__global__ void mm1s_kernel(const float* __restrict__ x, const float* __restrict__ W1,
                            const unsigned int* __restrict__ bm3,
                            const float* __restrict__ dis, float* __restrict__ hps) {
    __shared__ float w[F_IN * HID];
    for (int t = threadIdx.x; t < F_IN * HID; t += blockDim.x) w[t] = W1[t];
    __syncthreads();
    int row = blockIdx.x * blockDim.x + threadIdx.x;
    if (!((bm3[row >> 5] >> (row & 31)) & 1u)) return;
    const float4* xr = (const float4*)(x + (size_t)row * F_IN);
    float acc[HID] = {0.f,0.f,0.f,0.f,0.f,0.f,0.f,0.f};
    #pragma unroll 8
    for (int it = 0; it < F_IN / 4; ++it) {
        float4 xv = xr[it];
        const float* wr = &w[it * 4 * HID];
        #pragma unroll
        for (int j = 0; j < HID; ++j)
            acc[j] += xv.x * wr[j] + xv.y * wr[HID + j] + xv.z * wr[2 * HID + j] + xv.w * wr[3 * HID + j];
    }
    float di = dis[row];
    float4* o = (float4*)(hps + (size_t)row * HID);
    o[0] = make_float4(acc[0] * di, acc[1] * di, acc[2] * di, acc[3] * di);
    o[1] = make_float4(acc[4] * di, acc[5] * di, acc[6] * di, acc[7] * di);
}

// ---- gather1 (plane2 nodes): x1 = relu(di*(sum hps[s] + hps[i]) + b1);
//      hps2 = (x1 @ W2) * di; targets stash x1 row into x1t -------------------
__global__ void gather1_kernel(const int* __restrict__ rowptr, const int* __restrict__ csr,
                               const float* __restrict__ dis, const float* __restrict__ hps,
                               const unsigned int* __restrict__ bm2,
                               const unsigned int* __restrict__ bmT,
                               const float* __restrict__ b1v, const float* __restrict__ W2,
                               float* __restrict__ hps2, float* __restrict__ x1t) {
    __shared__ float w[HID * HID];
    if (threadIdx.x < HID * HID) w[threadIdx.x] = W2[threadIdx.x];
    __syncthreads();
    int i = blockIdx.x * blockDim.x + threadIdx.x;
    if (!((bm2[i >> 5] >> (i & 31)) & 1u)) return;
    float di = dis[i];
    int e0 = rowptr[i], e1 = rowptr[i + 1];
    float acc[HID] = {0.f,0.f,0.f,0.f,0.f,0.f,0.f,0.f};
    for (int k = e0; k < e1; ++k) {
        int s = csr[k];
        const float4* h = (const float4*)(hps + (size_t)s * HID);
        float4 a = h[0], b = h[1];
        acc[0] += a.x; acc[1] += a.y; acc[2] += a.z; acc[3] += a.w;
        acc[4] += b.x; acc[5] += b.y; acc[6] += b.z; acc[7] += b.w;
    }
    const float4* hs = (const float4*)(hps + (size_t)i * HID);
    float4 h0 = hs[0], h1 = hs[1];
    float v[HID];
    v[0] = fmaxf(di * (acc[0] + h0.x) + b1v[0], 0.f);
    v[1] = fmaxf(di * (acc[1] + h0.y) + b1v[1], 0.f);
    v[2] = fmaxf(di * (acc[2] + h0.z) + b1v[2], 0.f);
    v[3] = fmaxf(di * (acc[3] + h0.w) + b1v[3], 0.f);
    v[4] = fmaxf(di * (acc[4] + h1.x) + b1v[4], 0.f);
    v[5] = fmaxf(di * (acc[5] + h1.y) + b1v[5], 0.f);
    v[6] = fmaxf(di * (acc[6] + h1.z) + b1v[6], 0.f);
    v[7] = fmaxf(di * (acc[7] + h1.w) + b1v[7], 0.f);
    if ((bmT[i >> 5] >> (i & 31)) & 1u) {
        float* xt = x1t + (size_t)(i >> NPG_SHIFT) * HID;
        #pragma unroll
        for (int j = 0; j < HID; ++j) xt[j] = v[j];
    }
    float o[HID];
    #pragma unroll
    for (int j = 0; j < HID; ++j) {
        float sj = 0.f;
        #pragma unroll
        for (int k = 0; k < HID; ++k) sj += v[k] * w[k * HID + j];
        o[j] = sj * di;
    }
    float4* op = (float4*)(hps2 + (size_t)i * HID);
    op[0] = make_float4(o[0], o[1], o[2], o[3]);
    op[1] = make_float4(o[4], o[5], o[6], o[7]);
}

// ---- gather2 (plane1 nodes): x2 = relu(di*(sum hps2[s] + hps2[i]) + b2) ----
__global__ void gather2_kernel(const int* __restrict__ rowptr, const int* __restrict__ csr,
                               const float* __restrict__ dis, const float* __restrict__ hps2,
                               const unsigned int* __restrict__ bm1,
                               const float* __restrict__ b2v, float* __restrict__ x2) {
    int i = blockIdx.x * blockDim.x + threadIdx.x;
    if (!((bm1[i >> 5] >> (i & 31)) & 1u)) return;
    float di = dis[i];
    int e0 = rowptr[i], e1 = rowptr[i + 1];
    float acc[HID] = {0.f,0.f,0.f,0.f,0.f,0.f,0.f,0.f};
    for (int k = e0; k < e1; ++k) {
        int s = csr[k];
        const float4* h = (const float4*)(hps2 + (size_t)s * HID);
        float4 a = h[0], b = h[1];
        acc[0] += a.x; acc[1] += a.y; acc[2] += a.z; acc[3] += a.w;
        acc[4] += b.x; acc[5] += b.y; acc[6] += b.z; acc[7] += b.w;
    }
    const float4* hs = (const float4*)(hps2 + (size_t)i * HID);
    float4 h0 = hs[0], h1 = hs[1];
    float4* xo = (float4*)(x2 + (size_t)i * HID);
    xo[0] = make_float4(fmaxf(di * (acc[0] + h0.x) + b2v[0], 0.f),
                        fmaxf(di * (acc[1] + h0.y) + b2v[1], 0.f),
                        fmaxf(di * (acc[2] + h0.z) + b2v[2], 0.f),
                        fmaxf(di * (acc[3] + h0.w) + b2v[3], 0.f));
    xo[1] = make_float4(fmaxf(di * (acc[4] + h1.x) + b2v[4], 0.f),
                        fmaxf(di * (acc[5] + h1.y) + b2v[5], 0.f),
                        fmaxf(di * (acc[6] + h1.z) + b2v[6], 0.f),
                        fmaxf(di * (acc[7] + h1.w) + b2v[7], 0.f));
}

// ---- head: x3 at target via csr row + feats + MLP ----
__global__ void headf_kernel(const int* __restrict__ tgt, const int* __restrict__ rowptr,
                             const int* __restrict__ csr, const float* __restrict__ dis,
                             const float* __restrict__ x1t, const float* __restrict__ x2,
                             const float* __restrict__ W3, const float* __restrict__ b3,
                             const float* __restrict__ Wl1, const float* __restrict__ bl1,
                             const float* __restrict__ Wl2, const float* __restrict__ bl2,
                             float* __restrict__ out) {
    int g = threadIdx.x;
    if (g >= B_GRAPHS) return;
    size_t t = (size_t)g * NPG + tgt[g];
    float di = dis[t];
    float w3[HID];
    #pragma unroll
    for (int j = 0; j < HID; ++j) w3[j] = W3[j];
    float f[17];
    #pragma unroll
    for (int j = 0; j < HID; ++j) f[j] = x1t[(size_t)g * HID + j];
    #pragma unroll
    for (int j = 0; j < HID; ++j) f[8 + j] = x2[t * HID + j];
    int e0 = rowptr[t], e1 = rowptr[t + 1];
    float a3 = 0.f;
    for (int k = e0; k < e1; ++k) {
        int s = csr[k];
        float h = 0.f;
        #pragma unroll
        for (int j = 0; j < HID; ++j) h += x2[(size_t)s * HID + j] * w3[j];
        a3 += h * dis[s];
    }
    float h3 = 0.f;
    #pragma unroll
    for (int j = 0; j < HID; ++j) h3 += f[8 + j] * w3[j];
    f[16] = fmaxf(a3 * di + h3 * di * di + b3[0], 0.f);
    float o0 = bl2[0], o1 = bl2[1];
    #pragma unroll
    for (int j = 0; j < 16; ++j) {
        float z = bl1[j];
        #pragma unroll
        for (int k = 0; k < 17; ++k) z += f[k] * Wl1[k * 16 + j];
        z = fmaxf(z, 0.f);
        o0 += z * Wl2[j * 2 + 0];
        o1 += z * Wl2[j * 2 + 1];
    }
    out[g * 2 + 0] = o0;
    out[g * 2 + 1] = o1;
}

extern "C" void kernel_launch(void* const* d_in, const int* in_sizes, int n_in,
                              void* d_out, int out_size, void* d_ws, size_t ws_size,
                              hipStream_t stream) {
    const float* x  = (const float*)d_in[0];
    const int* ei   = (const int*)d_in[1];
    const int* src  = ei;
    const int* dst  = ei + E_EDGES;
    const int* tid  = (const int*)d_in[2];
    const float* W1 = (const float*)d_in[3];
    const float* b1 = (const float*)d_in[4];
    const float* W2 = (const float*)d_in[5];
    const float* b2 = (const float*)d_in[6];
    const float* W3 = (const float*)d_in[7];
    const float* b3 = (const float*)d_in[8];
    const float* Wl1 = (const float*)d_in[9];
    const float* bl1 = (const float*)d_in[10];
    const float* Wl2 = (const float*)d_in[11];
    const float* bl2 = (const float*)d_in[12];
    float* out = (float*)d_out;

    char* ws = (char*)d_ws;
    size_t off = 0;
    auto alloc = [&](size_t bytes) {
        void* p = ws + off;
        off += (bytes + 255) & ~(size_t)255;
        return p;
    };
    // bitmap planes (cleared each run, contiguous 256 KB)
    unsigned int* bm1 = (unsigned int*)alloc(65536);
    unsigned int* bm2 = (unsigned int*)alloc(65536);
    unsigned int* bm3 = (unsigned int*)alloc(65536);
    unsigned int* bmT = (unsigned int*)alloc(65536);
    float* x1t   = (float*)alloc((size_t)B_GRAPHS * HID * 4);      // 2 KB
    int* M       = (int*)alloc((size_t)BUCKETS * ABLK * 4);        // 2 MB
    int* btot    = (int*)alloc((size_t)BUCKETS * 4);
    int* base    = (int*)alloc((size_t)(BUCKETS + 1) * 4);
    int* rowptr  = (int*)alloc((size_t)(N_NODES + 1) * 4);         // 2 MB
    float* dis   = (float*)alloc((size_t)N_NODES * 4);             // 2 MB
    unsigned int* ebuf = (unsigned int*)alloc((size_t)E_EDGES * 4);// 33.5 MB (csr in-place)
    float* hps   = (float*)alloc((size_t)N_NODES * HID * 4);       // 16 MB (x2 aliases after gather1)
    float* hps2  = (float*)alloc((size_t)N_NODES * HID * 4);       // 16 MB
    int* csr = (int*)ebuf;
    float* x2 = hps;            // hps dead after gather1; reuse for x2
    (void)ws_size;

    clear_kernel<<<64, 256, 0, stream>>>((int4*)bm1);   // 16384 int4 = 4 planes
    hist_kernel<<<ABLK, ATHREADS, 0, stream>>>(dst, M);
    rowscan_kernel<<<BUCKETS, 256, 0, stream>>>(M, btot);
    basescan_kernel<<<1, 256, 0, stream>>>(btot, base);
    scatter_kernel<<<ABLK, ATHREADS, 0, stream>>>(src, dst, M, base, ebuf);
    build_kernel<<<BUCKETS, 256, 0, stream>>>(ebuf, base, rowptr, dis);
    bfs1_kernel<<<1, 64, 0, stream>>>(tid, rowptr, csr, bm1, bm2, bm3, bmT);
    bfs2_kernel<<<2048, 256, 0, stream>>>(rowptr, csr, bm1, bm2, bm3);
    bfs3_kernel<<<2048, 256, 0, stream>>>(rowptr, csr, bm2, bm3);
    mm1s_kernel<<<2048, 256, 0, stream>>>(x, W1, bm3, dis, hps);
    gather1_kernel<<<2048, 256, 0, stream>>>(rowptr, csr, dis, hps, bm2, bmT, b1, W2, hps2, x1t);
    gather2_kernel<<<2048, 256, 0, stream>>>(rowptr, csr, dis, hps2, bm1, b2, x2);
    headf_kernel<<<1, 64, 0, stream>>>(tid, rowptr, csr, dis, x1t, x2,
                                       W3, b3, Wl1, bl1, Wl2, bl2, out);
}